// Round 1
// baseline (541.226 us; speedup 1.0000x reference)
//
#include <hip/hip_runtime.h>
#include <cstddef>

constexpr int C = 64;   // channels
constexpr int B = 16;   // segments

// ---------------- Kernel A: per-segment column sums ----------------
// Each block owns a contiguous row range. Thread layout: 16 col-groups x 16 row-offsets.
// Register-accumulate per thread until the segment changes, flush to LDS, then one
// global atomicAdd pass per block.
__global__ __launch_bounds__(256) void seg_sum_kernel(
    const float* __restrict__ x, const int* __restrict__ o,
    float* __restrict__ sums, int N, int rows_per_block)
{
    __shared__ float lsum[B * C];
    const int tid = threadIdx.x;
    for (int i = tid; i < B * C; i += 256) lsum[i] = 0.0f;
    __syncthreads();

    const int c4 = (tid & 15) * 4;     // column group (4 consecutive cols)
    const int r0 = tid >> 4;           // 0..15 row offset
    const int row_begin = blockIdx.x * rows_per_block;
    const int row_end   = min(N, row_begin + rows_per_block);

    float ax = 0.f, ay = 0.f, az = 0.f, aw = 0.f;
    int seg = 0;
    int endcur = o[0];

    for (int r = row_begin + r0; r < row_end; r += 16) {
        while (r >= endcur) {
            if (ax != 0.f || ay != 0.f || az != 0.f || aw != 0.f) {
                atomicAdd(&lsum[seg * C + c4 + 0], ax);
                atomicAdd(&lsum[seg * C + c4 + 1], ay);
                atomicAdd(&lsum[seg * C + c4 + 2], az);
                atomicAdd(&lsum[seg * C + c4 + 3], aw);
                ax = ay = az = aw = 0.f;
            }
            ++seg;
            endcur = o[seg];
        }
        const float4 v = *reinterpret_cast<const float4*>(x + (size_t)r * C + c4);
        ax += v.x; ay += v.y; az += v.z; aw += v.w;
    }
    if (ax != 0.f || ay != 0.f || az != 0.f || aw != 0.f) {
        atomicAdd(&lsum[seg * C + c4 + 0], ax);
        atomicAdd(&lsum[seg * C + c4 + 1], ay);
        atomicAdd(&lsum[seg * C + c4 + 2], az);
        atomicAdd(&lsum[seg * C + c4 + 3], aw);
    }
    __syncthreads();

    for (int i = tid; i < B * C; i += 256) {
        const float v = lsum[i];
        if (v != 0.f) atomicAdd(&sums[i], v);
    }
}

// ---------------- Kernel B: tiny MLP on pooled vectors ----------------
// v[b][k] = sum_j relu(mean[b]@W2 + b2)[j] * W1[C+j][k] + b1[k]
__global__ __launch_bounds__(1024) void pooled_mlp_kernel(
    const int* __restrict__ o, const float* __restrict__ sums,
    const float* __restrict__ W2, const float* __restrict__ b2,
    const float* __restrict__ W1, const float* __restrict__ b1,
    float* __restrict__ vtab)
{
    __shared__ float means[B * C];
    __shared__ float xb[B * C];
    const int tid = threadIdx.x;          // 0..1023
    const int b = tid >> 6;               // segment
    const int j = tid & 63;               // channel

    const int cnt = o[b] - (b ? o[b - 1] : 0);
    means[tid] = sums[tid] / (float)cnt;
    __syncthreads();

    float acc = b2[j];
#pragma unroll
    for (int c = 0; c < C; ++c)
        acc = fmaf(means[b * C + c], W2[c * C + j], acc);
    xb[tid] = fmaxf(acc, 0.f);
    __syncthreads();

    float acc2 = b1[j];
#pragma unroll
    for (int jj = 0; jj < C; ++jj)
        acc2 = fmaf(xb[b * C + jj], W1[(C + jj) * C + j], acc2);
    vtab[tid] = acc2;
}

// ---------------- Kernel C: main per-point pass ----------------
// One wave per row; lane k computes output column k:
//   h[k] = x_row . W1_top[:,k] + vtab[seg][k]   then LayerNorm + ReLU.
__global__ __launch_bounds__(256) void main_kernel(
    const float* __restrict__ x, const int* __restrict__ o,
    const float* __restrict__ W1, const float* __restrict__ vtab,
    const float* __restrict__ gamma, const float* __restrict__ beta,
    float* __restrict__ out, int N, int rows_per_wave)
{
    __shared__ float vl[B * C];
    const int tid = threadIdx.x;
    for (int i = tid; i < B * C; i += 256) vl[i] = vtab[i];

    const int lane = tid & 63;
    // W1_top column k held in registers (64 VGPRs)
    float w[C];
#pragma unroll
    for (int c = 0; c < C; ++c) w[c] = W1[c * C + lane];
    const float g  = gamma[lane];
    const float bt = beta[lane];
    __syncthreads();

    const int wid = __builtin_amdgcn_readfirstlane(tid >> 6);
    const int gw = blockIdx.x * 4 + wid;
    const int row_begin = gw * rows_per_wave;
    if (row_begin >= N) return;
    const int row_end = min(N, row_begin + rows_per_wave);

    int seg = 0;
    while (row_begin >= o[seg]) ++seg;   // row_begin < N == o[B-1]
    int endcur = o[seg];
    float vcur = vl[seg * C + lane];

    for (int row = row_begin; row < row_end; ++row) {
        while (row >= endcur) {
            ++seg;
            endcur = o[seg];
            vcur = vl[seg * C + lane];
        }
        const float* xr = x + (size_t)row * C;
        float a0 = vcur, a1 = 0.f, a2 = 0.f, a3 = 0.f;
#pragma unroll
        for (int c = 0; c < C; c += 4) {
            const float4 xv = *reinterpret_cast<const float4*>(xr + c); // uniform addr -> broadcast
            a0 = fmaf(xv.x, w[c + 0], a0);
            a1 = fmaf(xv.y, w[c + 1], a1);
            a2 = fmaf(xv.z, w[c + 2], a2);
            a3 = fmaf(xv.w, w[c + 3], a3);
        }
        float h = (a0 + a1) + (a2 + a3);

        float s = h, q = h * h;
#pragma unroll
        for (int m = 1; m < 64; m <<= 1) {
            s += __shfl_xor(s, m, 64);
            q += __shfl_xor(q, m, 64);
        }
        const float mean = s * (1.0f / 64.0f);
        const float var  = q * (1.0f / 64.0f) - mean * mean;
        const float r    = rsqrtf(var + 1e-5f);
        const float y    = (h - mean) * r * g + bt;
        out[(size_t)row * C + lane] = fmaxf(y, 0.f);
    }
}

extern "C" void kernel_launch(void* const* d_in, const int* in_sizes, int n_in,
                              void* d_out, int out_size, void* d_ws, size_t ws_size,
                              hipStream_t stream) {
    const float* x     = (const float*)d_in[0];
    const int*   o     = (const int*)d_in[1];
    const float* W2    = (const float*)d_in[2];
    const float* b2    = (const float*)d_in[3];
    const float* W1    = (const float*)d_in[4];
    const float* b1    = (const float*)d_in[5];
    const float* gamma = (const float*)d_in[6];
    const float* beta  = (const float*)d_in[7];
    float* out = (float*)d_out;

    const int N = in_sizes[0] / C;

    float* sums = (float*)d_ws;
    float* vtab = sums + B * C;

    hipMemsetAsync(sums, 0, B * C * sizeof(float), stream);

    const int rpb = 1024;
    const int gridA = (N + rpb - 1) / rpb;
    seg_sum_kernel<<<gridA, 256, 0, stream>>>(x, o, sums, N, rpb);

    pooled_mlp_kernel<<<1, 1024, 0, stream>>>(o, sums, W2, b2, W1, b1, vtab);

    const int rpw = 128;
    const int nwaves = (N + rpw - 1) / rpw;
    const int gridC = (nwaves + 3) / 4;
    main_kernel<<<gridC, 256, 0, stream>>>(x, o, W1, vtab, gamma, beta, out, N, rpw);
}

// Round 2
// 184.015 us; speedup vs baseline: 2.9412x; 2.9412x over previous
//
#include <hip/hip_runtime.h>
#include <cstddef>

constexpr int C = 64;   // channels
constexpr int B = 16;   // segments

typedef __attribute__((ext_vector_type(8))) short bf16x8;
typedef __attribute__((ext_vector_type(4))) float f32x4;

__device__ inline unsigned short f2bf(float f) {
    unsigned u = __builtin_bit_cast(unsigned, f);
    unsigned r = (u + 0x7FFFu + ((u >> 16) & 1u)) >> 16;   // RNE
    return (unsigned short)r;
}

__device__ inline bf16x8 cvt8(float4 u, float4 v) {
    bf16x8 r;
    r[0] = (short)f2bf(u.x); r[1] = (short)f2bf(u.y);
    r[2] = (short)f2bf(u.z); r[3] = (short)f2bf(u.w);
    r[4] = (short)f2bf(v.x); r[5] = (short)f2bf(v.y);
    r[6] = (short)f2bf(v.z); r[7] = (short)f2bf(v.w);
    return r;
}

// ---------------- Kernel A: per-segment column sums ----------------
__global__ __launch_bounds__(256) void seg_sum_kernel(
    const float* __restrict__ x, const int* __restrict__ o,
    float* __restrict__ sums, int N, int rows_per_block)
{
    __shared__ float lsum[B * C];
    const int tid = threadIdx.x;
    for (int i = tid; i < B * C; i += 256) lsum[i] = 0.0f;
    __syncthreads();

    const int c4 = (tid & 15) * 4;
    const int r0 = tid >> 4;
    const int row_begin = blockIdx.x * rows_per_block;
    const int row_end   = min(N, row_begin + rows_per_block);

    float ax = 0.f, ay = 0.f, az = 0.f, aw = 0.f;
    int seg = 0;
    int endcur = o[0];

    for (int r = row_begin + r0; r < row_end; r += 16) {
        while (r >= endcur) {
            if (ax != 0.f || ay != 0.f || az != 0.f || aw != 0.f) {
                atomicAdd(&lsum[seg * C + c4 + 0], ax);
                atomicAdd(&lsum[seg * C + c4 + 1], ay);
                atomicAdd(&lsum[seg * C + c4 + 2], az);
                atomicAdd(&lsum[seg * C + c4 + 3], aw);
                ax = ay = az = aw = 0.f;
            }
            ++seg;
            endcur = o[seg];
        }
        const float4 v = *reinterpret_cast<const float4*>(x + (size_t)r * C + c4);
        ax += v.x; ay += v.y; az += v.z; aw += v.w;
    }
    if (ax != 0.f || ay != 0.f || az != 0.f || aw != 0.f) {
        atomicAdd(&lsum[seg * C + c4 + 0], ax);
        atomicAdd(&lsum[seg * C + c4 + 1], ay);
        atomicAdd(&lsum[seg * C + c4 + 2], az);
        atomicAdd(&lsum[seg * C + c4 + 3], aw);
    }
    __syncthreads();

    for (int i = tid; i < B * C; i += 256) {
        const float v = lsum[i];
        if (v != 0.f) atomicAdd(&sums[i], v);
    }
}

// ---------------- Kernel B: tiny MLP + W1-top bf16 fragment pack ----------------
// vtab[b][k] = relu(mean[b]@W2 + b2) @ W1_bot + b1
// wbf: W1_top packed into MFMA B-fragment order:
//   idx = ((ct*2+t)*64 + lane)*8 + j  ->  W1[t*32 + (lane>>4)*8 + j][ct*16 + (lane&15)]
__global__ __launch_bounds__(1024) void pooled_mlp_kernel(
    const int* __restrict__ o, const float* __restrict__ sums,
    const float* __restrict__ W2, const float* __restrict__ b2,
    const float* __restrict__ W1, const float* __restrict__ b1,
    float* __restrict__ vtab, unsigned short* __restrict__ wbf)
{
    __shared__ float means[B * C];
    __shared__ float xb[B * C];
    const int tid = threadIdx.x;
    const int b = tid >> 6;
    const int j = tid & 63;

    const int cnt = o[b] - (b ? o[b - 1] : 0);
    means[tid] = sums[tid] / (float)cnt;
    __syncthreads();

    float acc = b2[j];
#pragma unroll
    for (int c = 0; c < C; ++c)
        acc = fmaf(means[b * C + c], W2[c * C + j], acc);
    xb[tid] = fmaxf(acc, 0.f);
    __syncthreads();

    float acc2 = b1[j];
#pragma unroll
    for (int jj = 0; jj < C; ++jj)
        acc2 = fmaf(xb[b * C + jj], W1[(C + jj) * C + j], acc2);
    vtab[tid] = acc2;

    // pack W1_top as bf16 fragments (4096 entries, 4 per thread)
    for (int idx = tid; idx < 4096; idx += 1024) {
        const int jj2 = idx & 7;
        const int ln  = (idx >> 3) & 63;
        const int tt  = (idx >> 9) & 1;
        const int ct  = idx >> 10;
        const int k = tt * 32 + ((ln >> 4) * 8) + jj2;
        const int n = ct * 16 + (ln & 15);
        wbf[idx] = f2bf(W1[k * C + n]);
    }
}

// ---------------- Kernel C: MFMA main pass ----------------
// D[m=point][n=channel] tiles of 16x16, K=64 via two 16x16x32 bf16 MFMAs.
// D layout: col = lane&15 (channel within tile), row = (lane>>4)*4 + reg (point).
__global__ __launch_bounds__(256) void main_mfma_kernel(
    const float* __restrict__ x, const int* __restrict__ o,
    const unsigned short* __restrict__ wbf, const float* __restrict__ vtab,
    const float* __restrict__ gamma, const float* __restrict__ beta,
    float* __restrict__ out, int N, int rows_per_wave)
{
    __shared__ float vl[B * C];
    __shared__ int osh[B];
    const int tid = threadIdx.x;
    for (int i = tid; i < B * C; i += 256) vl[i] = vtab[i];
    if (tid < B) osh[tid] = o[tid];
    __syncthreads();

    const int lane = tid & 63;
    const int wid  = tid >> 6;
    const int chb  = lane & 15;          // channel base (tile-local)
    const int prow = (lane >> 4) * 4;    // point-row base within 16-tile

    // W fragments: [ct][t], 8 bf16 each
    bf16x8 wf[4][2];
#pragma unroll
    for (int ct = 0; ct < 4; ++ct)
#pragma unroll
        for (int t = 0; t < 2; ++t)
            wf[ct][t] = *reinterpret_cast<const bf16x8*>(wbf + ((ct * 2 + t) * 64 + lane) * 8);

    float g[4], bt[4];
#pragma unroll
    for (int ct = 0; ct < 4; ++ct) {
        g[ct]  = gamma[chb + 16 * ct];
        bt[ct] = beta [chb + 16 * ct];
    }

    const int gw = blockIdx.x * 4 + wid;
    const int p_begin = gw * rows_per_wave;
    if (p_begin >= N) return;
    const int p_end = min(N, p_begin + rows_per_wave);

    int seg = 0;
    while (p_begin >= osh[seg]) ++seg;
    float vb[4];
#pragma unroll
    for (int ct = 0; ct < 4; ++ct) vb[ct] = vl[seg * C + chb + 16 * ct];

    for (int p0 = p_begin; p0 < p_end; p0 += 16) {
        // A fragments: row = lane&15, k = (lane>>4)*8 + j (+ 32*t)
        const float* xr = x + (size_t)(p0 + (lane & 15)) * C + ((lane >> 4) * 8);
        const float4 a0 = *reinterpret_cast<const float4*>(xr);
        const float4 a1 = *reinterpret_cast<const float4*>(xr + 4);
        const float4 a2 = *reinterpret_cast<const float4*>(xr + 32);
        const float4 a3 = *reinterpret_cast<const float4*>(xr + 36);
        const bf16x8 A0 = cvt8(a0, a1);
        const bf16x8 A1 = cvt8(a2, a3);

        f32x4 acc[4];
#pragma unroll
        for (int ct = 0; ct < 4; ++ct) {
            acc[ct] = f32x4{0.f, 0.f, 0.f, 0.f};
            acc[ct] = __builtin_amdgcn_mfma_f32_16x16x32_bf16(A0, wf[ct][0], acc[ct], 0, 0, 0);
            acc[ct] = __builtin_amdgcn_mfma_f32_16x16x32_bf16(A1, wf[ct][1], acc[ct], 0, 0, 0);
        }

        // bias (per-segment)
        float h[4][4];   // [ct][reg]
        if (p0 + 16 <= osh[seg]) {       // whole 16-point window in one segment
#pragma unroll
            for (int r = 0; r < 4; ++r)
#pragma unroll
                for (int ct = 0; ct < 4; ++ct)
                    h[ct][r] = acc[ct][r] + vb[ct];
        } else {                          // boundary window (rare)
#pragma unroll
            for (int r = 0; r < 4; ++r) {
                const int p = p0 + prow + r;
                int s = seg;
                while (p >= osh[s]) ++s;
#pragma unroll
                for (int ct = 0; ct < 4; ++ct)
                    h[ct][r] = acc[ct][r] + vl[s * C + chb + 16 * ct];
            }
        }

        // LayerNorm over 64 channels: local 4-ct sum, then 16-lane tree
#pragma unroll
        for (int r = 0; r < 4; ++r) {
            float s_ = (h[0][r] + h[1][r]) + (h[2][r] + h[3][r]);
            float q_ = fmaf(h[0][r], h[0][r],
                       fmaf(h[1][r], h[1][r],
                       fmaf(h[2][r], h[2][r], h[3][r] * h[3][r])));
#pragma unroll
            for (int m = 1; m < 16; m <<= 1) {
                s_ += __shfl_xor(s_, m, 64);
                q_ += __shfl_xor(q_, m, 64);
            }
            const float mean = s_ * (1.0f / 64.0f);
            const float var  = q_ * (1.0f / 64.0f) - mean * mean;
            const float rs   = rsqrtf(var + 1e-5f);
            const int p = p0 + prow + r;
            float* op = out + (size_t)p * C + chb;
#pragma unroll
            for (int ct = 0; ct < 4; ++ct) {
                const float y = (h[ct][r] - mean) * rs * g[ct] + bt[ct];
                op[16 * ct] = fmaxf(y, 0.f);
            }
        }

        // advance segment for next window
        const int pn = p0 + 16;
        if (pn < p_end && pn >= osh[seg]) {
            while (pn >= osh[seg]) ++seg;
#pragma unroll
            for (int ct = 0; ct < 4; ++ct) vb[ct] = vl[seg * C + chb + 16 * ct];
        }
    }
}

extern "C" void kernel_launch(void* const* d_in, const int* in_sizes, int n_in,
                              void* d_out, int out_size, void* d_ws, size_t ws_size,
                              hipStream_t stream) {
    const float* x     = (const float*)d_in[0];
    const int*   o     = (const int*)d_in[1];
    const float* W2    = (const float*)d_in[2];
    const float* b2    = (const float*)d_in[3];
    const float* W1    = (const float*)d_in[4];
    const float* b1    = (const float*)d_in[5];
    const float* gamma = (const float*)d_in[6];
    const float* beta  = (const float*)d_in[7];
    float* out = (float*)d_out;

    const int N = in_sizes[0] / C;

    float* sums = (float*)d_ws;                         // 1024 f32
    float* vtab = sums + B * C;                         // 1024 f32
    unsigned short* wbf = (unsigned short*)(vtab + B * C);  // 4096 bf16

    hipMemsetAsync(sums, 0, B * C * sizeof(float), stream);

    const int rpb = 512;
    const int gridA = (N + rpb - 1) / rpb;
    seg_sum_kernel<<<gridA, 256, 0, stream>>>(x, o, sums, N, rpb);

    pooled_mlp_kernel<<<1, 1024, 0, stream>>>(o, sums, W2, b2, W1, b1, vtab, wbf);

    const int rpw = 128;                                // 16-point windows, 8 iters/wave
    const int nwaves = (N + rpw - 1) / rpw;
    const int gridC = (nwaves + 3) / 4;
    main_mfma_kernel<<<gridC, 256, 0, stream>>>(x, o, wbf, vtab, gamma, beta, out, N, rpw);
}

// Round 4
// 176.044 us; speedup vs baseline: 3.0744x; 1.0453x over previous
//
#include <hip/hip_runtime.h>
#include <hip/hip_bf16.h>
#include <cstddef>

constexpr int C = 64;   // channels
constexpr int B = 16;   // segments

typedef __attribute__((ext_vector_type(8))) short bf16x8;
typedef __attribute__((ext_vector_type(4))) float f32x4;
typedef __attribute__((ext_vector_type(4))) unsigned int u32x4;

__device__ inline unsigned short f2bf(float f) {
    unsigned u = __builtin_bit_cast(unsigned, f);
    unsigned r = (u + 0x7FFFu + ((u >> 16) & 1u)) >> 16;   // RNE
    return (unsigned short)r;
}

__device__ inline unsigned pk2(float a, float b) {
    __hip_bfloat162 t = __float22bfloat162_rn(float2{a, b});   // v_cvt_pk_bf16_f32
    unsigned u;
    __builtin_memcpy(&u, &t, 4);
    return u;
}

// packed f32->bf16 (compiler emits v_cvt_pk_bf16_f32)
__device__ inline bf16x8 cvt8(float4 u, float4 v) {
    u32x4 r;
    r[0] = pk2(u.x, u.y);
    r[1] = pk2(u.z, u.w);
    r[2] = pk2(v.x, v.y);
    r[3] = pk2(v.z, v.w);
    return __builtin_bit_cast(bf16x8, r);
}

// ---------------- Kernel A: per-segment column sums ----------------
__global__ __launch_bounds__(256) void seg_sum_kernel(
    const float* __restrict__ x, const int* __restrict__ o,
    float* __restrict__ sums, int N, int rows_per_block)
{
    __shared__ float lsum[B * C];
    const int tid = threadIdx.x;
    for (int i = tid; i < B * C; i += 256) lsum[i] = 0.0f;
    __syncthreads();

    const int c4 = (tid & 15) * 4;
    const int r0 = tid >> 4;
    const int row_begin = blockIdx.x * rows_per_block;
    const int row_end   = min(N, row_begin + rows_per_block);

    float ax = 0.f, ay = 0.f, az = 0.f, aw = 0.f;
    int seg = 0;
    int endcur = o[0];

    for (int r = row_begin + r0; r < row_end; r += 16) {
        while (r >= endcur) {
            if (ax != 0.f || ay != 0.f || az != 0.f || aw != 0.f) {
                atomicAdd(&lsum[seg * C + c4 + 0], ax);
                atomicAdd(&lsum[seg * C + c4 + 1], ay);
                atomicAdd(&lsum[seg * C + c4 + 2], az);
                atomicAdd(&lsum[seg * C + c4 + 3], aw);
                ax = ay = az = aw = 0.f;
            }
            ++seg;
            endcur = o[seg];
        }
        const float4 v = *reinterpret_cast<const float4*>(x + (size_t)r * C + c4);
        ax += v.x; ay += v.y; az += v.z; aw += v.w;
    }
    if (ax != 0.f || ay != 0.f || az != 0.f || aw != 0.f) {
        atomicAdd(&lsum[seg * C + c4 + 0], ax);
        atomicAdd(&lsum[seg * C + c4 + 1], ay);
        atomicAdd(&lsum[seg * C + c4 + 2], az);
        atomicAdd(&lsum[seg * C + c4 + 3], aw);
    }
    __syncthreads();

    for (int i = tid; i < B * C; i += 256) {
        const float v = lsum[i];
        if (v != 0.f) atomicAdd(&sums[i], v);
    }
}

// ---------------- Kernel B: tiny MLP + W1-top bf16 fragment pack ----------------
// vtab[b][k] = relu(mean[b]@W2 + b2) @ W1_bot + b1
// wbf: W1_top packed into MFMA B-fragment order with PERMUTED channels:
//   tile ct, col c (=lane&15)  ->  output channel 4*c + ct   (so each lane owns
//   4 contiguous channels across its 4 accumulators -> float4 stores)
__global__ __launch_bounds__(1024) void pooled_mlp_kernel(
    const int* __restrict__ o, const float* __restrict__ sums,
    const float* __restrict__ W2, const float* __restrict__ b2,
    const float* __restrict__ W1, const float* __restrict__ b1,
    float* __restrict__ vtab, unsigned short* __restrict__ wbf)
{
    __shared__ float means[B * C];
    __shared__ float xb[B * C];
    const int tid = threadIdx.x;
    const int b = tid >> 6;
    const int j = tid & 63;

    const int cnt = o[b] - (b ? o[b - 1] : 0);
    means[tid] = sums[tid] / (float)cnt;
    __syncthreads();

    float acc = b2[j];
#pragma unroll
    for (int c = 0; c < C; ++c)
        acc = fmaf(means[b * C + c], W2[c * C + j], acc);
    xb[tid] = fmaxf(acc, 0.f);
    __syncthreads();

    float acc2 = b1[j];
#pragma unroll
    for (int jj = 0; jj < C; ++jj)
        acc2 = fmaf(xb[b * C + jj], W1[(C + jj) * C + j], acc2);
    vtab[tid] = acc2;

    // pack W1_top as bf16 fragments (4096 entries, 4 per thread)
    for (int idx = tid; idx < 4096; idx += 1024) {
        const int jj2 = idx & 7;
        const int ln  = (idx >> 3) & 63;
        const int tt  = (idx >> 9) & 1;
        const int ct  = idx >> 10;
        const int k   = tt * 32 + ((ln >> 4) * 8) + jj2;
        const int ch  = 4 * (ln & 15) + ct;          // permuted channel
        wbf[idx] = f2bf(W1[k * C + ch]);
    }
}

// ---------------- Kernel C: MFMA main pass ----------------
// D[m=point][n] tiles of 16x16, K=64 via two 16x16x32 bf16 MFMAs.
// D layout: col = lane&15, row = (lane>>4)*4 + reg.  Channel = 4*(lane&15) + ct.
__global__ __launch_bounds__(256) void main_mfma_kernel(
    const float* __restrict__ x, const int* __restrict__ o,
    const unsigned short* __restrict__ wbf, const float* __restrict__ vtab,
    const float* __restrict__ gamma, const float* __restrict__ beta,
    float* __restrict__ out, int N, int rows_per_wave)
{
    __shared__ float vl[B * C];
    __shared__ int osh[B];
    const int tid = threadIdx.x;
    for (int i = tid; i < B * C; i += 256) vl[i] = vtab[i];
    if (tid < B) osh[tid] = o[tid];
    __syncthreads();

    const int lane = tid & 63;
    const int wid  = tid >> 6;
    const int chb  = lane & 15;          // column within tile
    const int prow = (lane >> 4) * 4;    // point-row base within 16-tile

    // W fragments: [ct][t], 8 bf16 each
    bf16x8 wf[4][2];
#pragma unroll
    for (int ct = 0; ct < 4; ++ct)
#pragma unroll
        for (int t = 0; t < 2; ++t)
            wf[ct][t] = *reinterpret_cast<const bf16x8*>(wbf + ((ct * 2 + t) * 64 + lane) * 8);

    // channels 4*chb .. 4*chb+3 -> float4 loads
    const float4 g4  = *reinterpret_cast<const float4*>(gamma + 4 * chb);
    const float4 bt4 = *reinterpret_cast<const float4*>(beta  + 4 * chb);

    const int gw = blockIdx.x * 4 + wid;
    const int p_begin = gw * rows_per_wave;
    if (p_begin >= N) return;
    const int p_end = min(N, p_begin + rows_per_wave);

    int seg = 0;
    while (p_begin >= osh[seg]) ++seg;
    float4 vb = *reinterpret_cast<const float4*>(vl + seg * C + 4 * chb);

    for (int p0 = p_begin; p0 < p_end; p0 += 16) {
        // A fragments: row = lane&15, k = (lane>>4)*8 + j (+ 32*t)
        const float* xr = x + (size_t)(p0 + chb) * C + ((lane >> 4) * 8);
        const float4 a0 = *reinterpret_cast<const float4*>(xr);
        const float4 a1 = *reinterpret_cast<const float4*>(xr + 4);
        const float4 a2 = *reinterpret_cast<const float4*>(xr + 32);
        const float4 a3 = *reinterpret_cast<const float4*>(xr + 36);
        const bf16x8 A0 = cvt8(a0, a1);
        const bf16x8 A1 = cvt8(a2, a3);

        f32x4 acc[4];
#pragma unroll
        for (int ct = 0; ct < 4; ++ct) {
            acc[ct] = f32x4{0.f, 0.f, 0.f, 0.f};
            acc[ct] = __builtin_amdgcn_mfma_f32_16x16x32_bf16(A0, wf[ct][0], acc[ct], 0, 0, 0);
            acc[ct] = __builtin_amdgcn_mfma_f32_16x16x32_bf16(A1, wf[ct][1], acc[ct], 0, 0, 0);
        }

        // bias (per-segment)
        float h[4][4];   // [ct][reg]
        if (p0 + 16 <= osh[seg]) {       // whole window in one segment
#pragma unroll
            for (int r = 0; r < 4; ++r) {
                h[0][r] = acc[0][r] + vb.x;
                h[1][r] = acc[1][r] + vb.y;
                h[2][r] = acc[2][r] + vb.z;
                h[3][r] = acc[3][r] + vb.w;
            }
        } else {                          // boundary window (rare)
#pragma unroll
            for (int r = 0; r < 4; ++r) {
                const int p = p0 + prow + r;
                int s = seg;
                while (p >= osh[s]) ++s;
                const float4 vbs = *reinterpret_cast<const float4*>(vl + s * C + 4 * chb);
                h[0][r] = acc[0][r] + vbs.x;
                h[1][r] = acc[1][r] + vbs.y;
                h[2][r] = acc[2][r] + vbs.z;
                h[3][r] = acc[3][r] + vbs.w;
            }
        }

        // LayerNorm over 64 channels: local 4-elt sum, then 16-lane tree
#pragma unroll
        for (int r = 0; r < 4; ++r) {
            float s_ = (h[0][r] + h[1][r]) + (h[2][r] + h[3][r]);
            float q_ = fmaf(h[0][r], h[0][r],
                       fmaf(h[1][r], h[1][r],
                       fmaf(h[2][r], h[2][r], h[3][r] * h[3][r])));
#pragma unroll
            for (int m = 1; m < 16; m <<= 1) {
                s_ += __shfl_xor(s_, m, 64);
                q_ += __shfl_xor(q_, m, 64);
            }
            const float mean = s_ * (1.0f / 64.0f);
            const float var  = q_ * (1.0f / 64.0f) - mean * mean;
            const float rs   = rsqrtf(var + 1e-5f);
            const int p = p0 + prow + r;

            float4 y;
            y.x = fmaxf((h[0][r] - mean) * rs * g4.x + bt4.x, 0.f);
            y.y = fmaxf((h[1][r] - mean) * rs * g4.y + bt4.y, 0.f);
            y.z = fmaxf((h[2][r] - mean) * rs * g4.z + bt4.z, 0.f);
            y.w = fmaxf((h[3][r] - mean) * rs * g4.w + bt4.w, 0.f);
            *reinterpret_cast<float4*>(out + (size_t)p * C + 4 * chb) = y;
        }

        // advance segment for next window
        const int pn = p0 + 16;
        if (pn < p_end && pn >= osh[seg]) {
            while (pn >= osh[seg]) ++seg;
            vb = *reinterpret_cast<const float4*>(vl + seg * C + 4 * chb);
        }
    }
}

extern "C" void kernel_launch(void* const* d_in, const int* in_sizes, int n_in,
                              void* d_out, int out_size, void* d_ws, size_t ws_size,
                              hipStream_t stream) {
    const float* x     = (const float*)d_in[0];
    const int*   o     = (const int*)d_in[1];
    const float* W2    = (const float*)d_in[2];
    const float* b2    = (const float*)d_in[3];
    const float* W1    = (const float*)d_in[4];
    const float* b1    = (const float*)d_in[5];
    const float* gamma = (const float*)d_in[6];
    const float* beta  = (const float*)d_in[7];
    float* out = (float*)d_out;

    const int N = in_sizes[0] / C;

    float* sums = (float*)d_ws;                              // 1024 f32
    float* vtab = sums + B * C;                              // 1024 f32
    unsigned short* wbf = (unsigned short*)(vtab + B * C);   // 4096 bf16

    (void)hipMemsetAsync(sums, 0, B * C * sizeof(float), stream);

    const int rpb = 512;
    const int gridA = (N + rpb - 1) / rpb;
    seg_sum_kernel<<<gridA, 256, 0, stream>>>(x, o, sums, N, rpb);

    pooled_mlp_kernel<<<1, 1024, 0, stream>>>(o, sums, W2, b2, W1, b1, vtab, wbf);

    const int rpw = 128;
    const int nwaves = (N + rpw - 1) / rpw;
    const int gridC = (nwaves + 3) / 4;
    main_mfma_kernel<<<gridC, 256, 0, stream>>>(x, o, wbf, vtab, gamma, beta, out, N, rpw);
}

// Round 6
// 152.735 us; speedup vs baseline: 3.5436x; 1.1526x over previous
//
#include <hip/hip_runtime.h>
#include <hip/hip_bf16.h>
#include <cstddef>

constexpr int C = 64;   // channels
constexpr int B = 16;   // segments

typedef __attribute__((ext_vector_type(8))) short bf16x8;
typedef __attribute__((ext_vector_type(4))) float f32x4;
typedef __attribute__((ext_vector_type(4))) unsigned int u32x4;

__device__ inline unsigned short f2bf(float f) {
    unsigned u = __builtin_bit_cast(unsigned, f);
    unsigned r = (u + 0x7FFFu + ((u >> 16) & 1u)) >> 16;   // RNE
    return (unsigned short)r;
}

__device__ inline unsigned pk2(float a, float b) {
    __hip_bfloat162 t = __float22bfloat162_rn(float2{a, b});   // v_cvt_pk_bf16_f32
    unsigned u;
    __builtin_memcpy(&u, &t, 4);
    return u;
}

__device__ inline bf16x8 cvt8(float4 u, float4 v) {
    u32x4 r;
    r[0] = pk2(u.x, u.y);
    r[1] = pk2(u.z, u.w);
    r[2] = pk2(v.x, v.y);
    r[3] = pk2(v.z, v.w);
    return __builtin_bit_cast(bf16x8, r);
}

// ---------------- Kernel A: per-segment column sums ----------------
__global__ __launch_bounds__(256) void seg_sum_kernel(
    const float* __restrict__ x, const int* __restrict__ o,
    float* __restrict__ sums, int N, int rows_per_block)
{
    __shared__ float lsum[B * C];
    const int tid = threadIdx.x;
    for (int i = tid; i < B * C; i += 256) lsum[i] = 0.0f;
    __syncthreads();

    const int c4 = (tid & 15) * 4;
    const int r0 = tid >> 4;
    const int row_begin = blockIdx.x * rows_per_block;
    const int row_end   = min(N, row_begin + rows_per_block);

    float ax = 0.f, ay = 0.f, az = 0.f, aw = 0.f;
    int seg = 0;
    int endcur = o[0];

    for (int r = row_begin + r0; r < row_end; r += 16) {
        while (r >= endcur) {
            if (ax != 0.f || ay != 0.f || az != 0.f || aw != 0.f) {
                atomicAdd(&lsum[seg * C + c4 + 0], ax);
                atomicAdd(&lsum[seg * C + c4 + 1], ay);
                atomicAdd(&lsum[seg * C + c4 + 2], az);
                atomicAdd(&lsum[seg * C + c4 + 3], aw);
                ax = ay = az = aw = 0.f;
            }
            ++seg;
            endcur = o[seg];
        }
        const float4 v = *reinterpret_cast<const float4*>(x + (size_t)r * C + c4);
        ax += v.x; ay += v.y; az += v.z; aw += v.w;
    }
    if (ax != 0.f || ay != 0.f || az != 0.f || aw != 0.f) {
        atomicAdd(&lsum[seg * C + c4 + 0], ax);
        atomicAdd(&lsum[seg * C + c4 + 1], ay);
        atomicAdd(&lsum[seg * C + c4 + 2], az);
        atomicAdd(&lsum[seg * C + c4 + 3], aw);
    }
    __syncthreads();

    for (int i = tid; i < B * C; i += 256) {
        const float v = lsum[i];
        if (v != 0.f) atomicAdd(&sums[i], v);
    }
}

// ---------------- Kernel C: fused MLP-prologue + MFMA main pass ----------------
// Prologue (per block, replicated): means = sums/cnt; xb = relu(means@W2+b2);
// vl = xb@W1_bot + b1; wbf = W1_top packed to MFMA B-fragments (permuted channels:
// tile ct, col c -> channel 4c+ct so each lane owns 4 contiguous channels).
// Main: D[m=point][n] 16x16 tiles, K=64 via two 16x16x32 bf16 MFMAs, then
// per-segment bias + LayerNorm + ReLU, nontemporal float4 stores.
__global__ __launch_bounds__(256) void main_mfma_kernel(
    const float* __restrict__ x, const int* __restrict__ o,
    const float* __restrict__ sums,
    const float* __restrict__ W2, const float* __restrict__ b2,
    const float* __restrict__ W1, const float* __restrict__ b1,
    const float* __restrict__ gamma, const float* __restrict__ beta,
    float* __restrict__ out, int N, int rows_per_wave)
{
    __shared__ float ms[B * C];            // means
    __shared__ float xbs[B * C];           // hidden
    __shared__ float vl[B * C];            // per-segment bias table
    __shared__ unsigned short wbfs[4096];  // W1_top bf16 fragments
    __shared__ int osh[B];

    const int tid = threadIdx.x;
    if (tid < B) osh[tid] = o[tid];
    __syncthreads();

    const int j = tid & 63;                // fixed channel per thread
    const int bq = tid >> 6;               // 0..3: quarter of segments

    // means (4 segments per thread, same j)
#pragma unroll
    for (int q = 0; q < 4; ++q) {
        const int b = bq * 4 + q;
        const int cnt = osh[b] - (b ? osh[b - 1] : 0);
        ms[b * C + j] = sums[b * C + j] / (float)cnt;
    }
    __syncthreads();

    // xb = relu(means @ W2 + b2) : share each W2[c][j] load across 4 segments
    {
        float acc[4];
        const float bj = b2[j];
#pragma unroll
        for (int q = 0; q < 4; ++q) acc[q] = bj;
        for (int c = 0; c < C; ++c) {
            const float wv = W2[c * C + j];
#pragma unroll
            for (int q = 0; q < 4; ++q)
                acc[q] = fmaf(ms[(bq * 4 + q) * C + c], wv, acc[q]);
        }
#pragma unroll
        for (int q = 0; q < 4; ++q) xbs[(bq * 4 + q) * C + j] = fmaxf(acc[q], 0.f);
    }
    __syncthreads();

    // vl = xb @ W1_bot + b1
    {
        float acc[4];
        const float bj = b1[j];
#pragma unroll
        for (int q = 0; q < 4; ++q) acc[q] = bj;
        for (int jj = 0; jj < C; ++jj) {
            const float wv = W1[(C + jj) * C + j];
#pragma unroll
            for (int q = 0; q < 4; ++q)
                acc[q] = fmaf(xbs[(bq * 4 + q) * C + jj], wv, acc[q]);
        }
#pragma unroll
        for (int q = 0; q < 4; ++q) vl[(bq * 4 + q) * C + j] = acc[q];
    }

    // pack W1_top bf16 fragments (16 entries per thread)
    for (int idx = tid; idx < 4096; idx += 256) {
        const int jj2 = idx & 7;
        const int ln  = (idx >> 3) & 63;
        const int tt  = (idx >> 9) & 1;
        const int ct  = idx >> 10;
        const int k   = tt * 32 + ((ln >> 4) * 8) + jj2;
        const int ch  = 4 * (ln & 15) + ct;          // permuted channel
        wbfs[idx] = f2bf(W1[k * C + ch]);
    }
    __syncthreads();

    const int lane = tid & 63;
    const int wid  = tid >> 6;
    const int chb  = lane & 15;
    const int prow = (lane >> 4) * 4;

    bf16x8 wf[4][2];
#pragma unroll
    for (int ct = 0; ct < 4; ++ct)
#pragma unroll
        for (int t = 0; t < 2; ++t)
            wf[ct][t] = *reinterpret_cast<const bf16x8*>(wbfs + ((ct * 2 + t) * 64 + lane) * 8);

    const float4 g4  = *reinterpret_cast<const float4*>(gamma + 4 * chb);
    const float4 bt4 = *reinterpret_cast<const float4*>(beta  + 4 * chb);

    const int gw = blockIdx.x * 4 + wid;
    const int p_begin = gw * rows_per_wave;
    if (p_begin >= N) return;
    const int p_end = min(N, p_begin + rows_per_wave);

    int seg = 0;
    while (p_begin >= osh[seg]) ++seg;
    float4 vb = *reinterpret_cast<const float4*>(vl + seg * C + 4 * chb);

    for (int p0 = p_begin; p0 < p_end; p0 += 16) {
        const float* xr = x + (size_t)(p0 + chb) * C + ((lane >> 4) * 8);
        const float4 a0 = *reinterpret_cast<const float4*>(xr);
        const float4 a1 = *reinterpret_cast<const float4*>(xr + 4);
        const float4 a2 = *reinterpret_cast<const float4*>(xr + 32);
        const float4 a3 = *reinterpret_cast<const float4*>(xr + 36);
        const bf16x8 A0 = cvt8(a0, a1);
        const bf16x8 A1 = cvt8(a2, a3);

        f32x4 acc[4];
#pragma unroll
        for (int ct = 0; ct < 4; ++ct) {
            acc[ct] = f32x4{0.f, 0.f, 0.f, 0.f};
            acc[ct] = __builtin_amdgcn_mfma_f32_16x16x32_bf16(A0, wf[ct][0], acc[ct], 0, 0, 0);
            acc[ct] = __builtin_amdgcn_mfma_f32_16x16x32_bf16(A1, wf[ct][1], acc[ct], 0, 0, 0);
        }

        float h[4][4];   // [ct][reg]
        if (p0 + 16 <= osh[seg]) {
#pragma unroll
            for (int r = 0; r < 4; ++r) {
                h[0][r] = acc[0][r] + vb.x;
                h[1][r] = acc[1][r] + vb.y;
                h[2][r] = acc[2][r] + vb.z;
                h[3][r] = acc[3][r] + vb.w;
            }
        } else {
#pragma unroll
            for (int r = 0; r < 4; ++r) {
                const int p = p0 + prow + r;
                int s = seg;
                while (p >= osh[s]) ++s;
                const float4 vbs = *reinterpret_cast<const float4*>(vl + s * C + 4 * chb);
                h[0][r] = acc[0][r] + vbs.x;
                h[1][r] = acc[1][r] + vbs.y;
                h[2][r] = acc[2][r] + vbs.z;
                h[3][r] = acc[3][r] + vbs.w;
            }
        }

#pragma unroll
        for (int r = 0; r < 4; ++r) {
            float s_ = (h[0][r] + h[1][r]) + (h[2][r] + h[3][r]);
            float q_ = fmaf(h[0][r], h[0][r],
                       fmaf(h[1][r], h[1][r],
                       fmaf(h[2][r], h[2][r], h[3][r] * h[3][r])));
#pragma unroll
            for (int m = 1; m < 16; m <<= 1) {
                s_ += __shfl_xor(s_, m, 64);
                q_ += __shfl_xor(q_, m, 64);
            }
            const float mean = s_ * (1.0f / 64.0f);
            const float var  = q_ * (1.0f / 64.0f) - mean * mean;
            const float rs   = rsqrtf(var + 1e-5f);
            const int p = p0 + prow + r;

            f32x4 y;
            y[0] = fmaxf((h[0][r] - mean) * rs * g4.x + bt4.x, 0.f);
            y[1] = fmaxf((h[1][r] - mean) * rs * g4.y + bt4.y, 0.f);
            y[2] = fmaxf((h[2][r] - mean) * rs * g4.z + bt4.z, 0.f);
            y[3] = fmaxf((h[3][r] - mean) * rs * g4.w + bt4.w, 0.f);
            __builtin_nontemporal_store(y, reinterpret_cast<f32x4*>(out + (size_t)p * C + 4 * chb));
        }

        const int pn = p0 + 16;
        if (pn < p_end && pn >= osh[seg]) {
            while (pn >= osh[seg]) ++seg;
            vb = *reinterpret_cast<const float4*>(vl + seg * C + 4 * chb);
        }
    }
}

extern "C" void kernel_launch(void* const* d_in, const int* in_sizes, int n_in,
                              void* d_out, int out_size, void* d_ws, size_t ws_size,
                              hipStream_t stream) {
    const float* x     = (const float*)d_in[0];
    const int*   o     = (const int*)d_in[1];
    const float* W2    = (const float*)d_in[2];
    const float* b2    = (const float*)d_in[3];
    const float* W1    = (const float*)d_in[4];
    const float* b1    = (const float*)d_in[5];
    const float* gamma = (const float*)d_in[6];
    const float* beta  = (const float*)d_in[7];
    float* out = (float*)d_out;

    const int N = in_sizes[0] / C;

    float* sums = (float*)d_ws;   // 1024 f32

    (void)hipMemsetAsync(sums, 0, B * C * sizeof(float), stream);

    const int rpb = 512;
    const int gridA = (N + rpb - 1) / rpb;
    seg_sum_kernel<<<gridA, 256, 0, stream>>>(x, o, sums, N, rpb);

    const int rpw = 128;
    const int nwaves = (N + rpw - 1) / rpw;
    const int gridC = (nwaves + 3) / 4;
    main_mfma_kernel<<<gridC, 256, 0, stream>>>(x, o, sums, W2, b2, W1, b1,
                                                gamma, beta, out, N, rpw);
}